// Round 5
// baseline (458.196 us; speedup 1.0000x reference)
//
#include <hip/hip_runtime.h>
#include <hip/hip_bf16.h>

// Problem constants: B=32, S=4096, E=512, D=512, H=512
#define BATCH 32
#define SEQ   4096
#define EDIM  512
#define HDIM  512
#define NCHUNK 64                 // S-chunks of 64 rows per batch
#define NBLK  (BATCH * NCHUNK)    // 2048 fused blocks

typedef unsigned short u16;
typedef unsigned int   u32;

typedef __bf16 bf16x8 __attribute__((ext_vector_type(8)));
typedef float  f32x4  __attribute__((ext_vector_type(4)));

// one-instruction fp32x2 -> packed bf16x2 (RNE; bit-identical to manual RNE)
__device__ __forceinline__ u32 cvtpk(float lo, float hi) {
    u32 r;
    asm("v_cvt_pk_bf16_f32 %0, %1, %2" : "=v"(r) : "v"(lo), "v"(hi));
    return r;
}
__device__ __forceinline__ float tanh_fast(float x) {
    float e = __builtin_amdgcn_exp2f(x * 2.88539008177793f);
    return 1.0f - 2.0f * __builtin_amdgcn_rcpf(e + 1.0f);
}

// raw barrier: LDS-drain only. NOT __syncthreads() — that emits an implicit
// s_waitcnt vmcnt(0) which would drain our in-flight HBM/L2 prefetches at
// every step (the m97 barrier-drain trap). sched_barrier(0) pins the ds_write
// / ds_read on the correct side of the asm wait (rule #18).
#define LDS_BARRIER() do {                                   \
    __builtin_amdgcn_sched_barrier(0);                       \
    asm volatile("s_waitcnt lgkmcnt(0)" ::: "memory");       \
    __builtin_amdgcn_s_barrier();                            \
    __builtin_amdgcn_sched_barrier(0);                       \
} while (0)

// ---------------------------------------------------------------------------
// prep_kernel: (a) dec_bias = dec @ W_dec^T + b_dec + b_enc   [blocks 0..4095]
//              (b) pack W_enc fp32 -> bf16 b-fragment layout  [blocks 4096..4223]
// wpack chunk id = (nsub*16 + kc)*64 + lane;
// lane holds W[nsub*16+(l&15)][kc*32+(l>>4)*8+j], j=0..7
// ---------------------------------------------------------------------------
__global__ void prep_kernel(const float* __restrict__ W_enc, uint4* __restrict__ wpack,
                            const float* __restrict__ dec, const float* __restrict__ Wd,
                            const float* __restrict__ b_enc, const float* __restrict__ b_dec,
                            float* __restrict__ dec_bias) {
    int bid = blockIdx.x;
    int t = threadIdx.x;
    if (bid < 4096) {
        int wave = t >> 6, lane = t & 63;
        int p = bid * 4 + wave;
        int b = p >> 9, h = p & 511;
        const float4* wr = reinterpret_cast<const float4*>(Wd)  + h * 128;
        const float4* dr = reinterpret_cast<const float4*>(dec) + b * 128;
        float4 w0 = wr[lane * 2], w1 = wr[lane * 2 + 1];
        float4 d0 = dr[lane * 2], d1 = dr[lane * 2 + 1];
        float s = w0.x * d0.x + w0.y * d0.y + w0.z * d0.z + w0.w * d0.w
                + w1.x * d1.x + w1.y * d1.y + w1.z * d1.z + w1.w * d1.w;
#pragma unroll
        for (int m = 1; m < 64; m <<= 1) s += __shfl_xor(s, m, 64);
        if (lane == 0) dec_bias[p] = s + b_dec[h] + b_enc[h];
    } else {
        int id   = (bid - 4096) * 256 + t;          // 32768 chunks
        int nsub = id >> 10;
        int rem  = id & 1023;
        int kc   = rem >> 6;
        int lane = rem & 63;
        int row  = nsub * 16 + (lane & 15);
        int col  = kc * 32 + (lane >> 4) * 8;
        const float* src = W_enc + row * EDIM + col;
        uint4 o;
        o.x = cvtpk(src[0], src[1]);
        o.y = cvtpk(src[2], src[3]);
        o.z = cvtpk(src[4], src[5]);
        o.w = cvtpk(src[6], src[7]);
        wpack[id] = o;
    }
}

// ---------------------------------------------------------------------------
// fused_kernel v5 (resubmit — round-4 bench was an infra failure, kernel
// re-audited: no OOB, no barrier divergence, double-buffer race-free, vmcnt
// FIFO invariant holds).
//  Per block = (batch b, 64-row S-chunk), 512 threads / 8 waves.
//  ROUND-3 POST-MORTEM: no pipe >25%; phases (stage 41us HBM + 15us cvt VALU,
//  K-loop 33us MFMA + 30us W-L2, epilogue) run SERIALLY and their times add.
//  v5 overlaps them: rolling 64-col chunk double-buffer; per super-step k
//  (2 K-steps, cols k*64..k*64+63):
//    1. issue W frags for ks=2k+1            (L2)
//    2. ds_read af lo + 16 MFMA (ks=2k)      [waits W(2k) only — vmcnt FIFO:
//                                             all in-flight X is YOUNGER]
//    3. cvt X(k+1) regs -> uint4 (cvt_pk)    [X(k+1) ~1 step old]
//    4. issue W frags for ks=2k+2
//    5. issue X(k+2) float4 pair             (HBM, 2 steps of cover)
//    6. ds_read af hi + 16 MFMA (ks=2k+1)
//    7. ds_write X(k+1) -> buf[(k+1)&1]
//    8. LDS_BARRIER (lgkmcnt only; HBM/L2 prefetch stays in flight)
//  vmcnt-order invariant: every W-wait is older than every in-flight X load,
//  so no wait ever drains the HBM pipeline (steady state: W-wait leaves 6
//  younger outstanding, X-wait leaves 4).
//  LDS: 2 x 64 x 72 u16 = 18 KB (+sred/pbuf). Row stride 72 u16 = 144 B:
//  16B-aligned for b128; dword stride 36 == 4 (mod 32): af b128 reads spread
//  8 dwords/bank (2-way same-bank = free, m136); staging b128 writes balanced.
//  Regs: acc 64 + bA/bB 32 + X 16 + af 16 transient + addr ~= 120 < 128 cap.
//  mfma_f32_16x16x32_bf16: A[m=l&15][k=(l>>4)*8+j]; C/D: m=(l>>4)*4+r, n=l&15.
// ---------------------------------------------------------------------------
#define ST 72

__global__ __launch_bounds__(512, 4) void fused_kernel(
    const float* __restrict__ X, const uint4* __restrict__ Wp,
    const float* __restrict__ bias, const float* __restrict__ v,
    float* __restrict__ cpart, float* __restrict__ mpart, float* __restrict__ lpart)
{
    __shared__ alignas(16) u16 Abuf[2][64 * ST];     // 2 x 9216 B
    __shared__ float sred[8][64];                    // 2 KB
    __shared__ float pbuf[64];

    const int tid  = threadIdx.x;
    const int wave = tid >> 6, lane = tid & 63;
    const int quad = lane >> 4, l15 = lane & 15;
    const int blk  = blockIdx.x;          // 2048
    const int b    = blk >> 6;
    const long row0 = (long)blk * 64;
    const float4* X4 = reinterpret_cast<const float4*>(X + row0 * EDIM);

    // staging map: thread -> row r (0..63), 8-float group c8 (0..7) within the
    // 64-col super-chunk. Chunk k cols = k*64 .. k*64+63.
    const int r  = tid >> 3;
    const int c8 = tid & 7;
    const float4* Xr = X4 + r * 128 + c8 * 2;        // + k*16 per chunk
    u16* Aw0 = &Abuf[0][r * ST + c8 * 8];
    u16* Aw1 = &Abuf[1][r * ST + c8 * 8];

    // ---- prologue: X(0) -> buf0; W(0); X(1) in regs (issued AFTER W(0) so
    //      the k=0 W-wait never drains the X(1) HBM loads) ----
    float4 a0 = Xr[0], a1 = Xr[1];                   // X chunk 0 (oldest)
    uint4 bA[4], bB[4];
#pragma unroll
    for (int jj = 0; jj < 4; jj++)
        bA[jj] = Wp[((wave * 4 + jj) * 16 + 0) * 64 + lane];
    float4 pA = Xr[16], pB = Xr[17];                 // X chunk 1 (youngest)
    {
        uint4 w;
        w.x = cvtpk(a0.x, a0.y);  w.y = cvtpk(a0.z, a0.w);
        w.z = cvtpk(a1.x, a1.y);  w.w = cvtpk(a1.z, a1.w);
        *reinterpret_cast<uint4*>(Aw0) = w;
    }
    f32x4 acc[4][4] = {};                 // [msub][nsub]: m=64, n=64 per wave
    LDS_BARRIER();

    // ---- main loop: 8 super-steps of 2 K-steps each ----
#pragma unroll
    for (int k = 0; k < 8; k++) {
        const u16* Ab = Abuf[k & 1];

        // (1) W fragments for ks=2k+1
#pragma unroll
        for (int jj = 0; jj < 4; jj++)
            bB[jj] = Wp[((wave * 4 + jj) * 16 + (2 * k + 1)) * 64 + lane];

        // (2) ks=2k: ds_read + MFMA on bA
        bf16x8 af[4];
#pragma unroll
        for (int i = 0; i < 4; i++)
            af[i] = *reinterpret_cast<const bf16x8*>(
                &Ab[(i * 16 + l15) * ST + quad * 8]);
#pragma unroll
        for (int jj = 0; jj < 4; jj++) {
            bf16x8 bfr = __builtin_bit_cast(bf16x8, bA[jj]);
#pragma unroll
            for (int i = 0; i < 4; i++)
                acc[i][jj] = __builtin_amdgcn_mfma_f32_16x16x32_bf16(
                    af[i], bfr, acc[i][jj], 0, 0, 0);
        }

        // (3) convert X(k+1) (loaded one step ago) -> packed bf16
        uint4 wq;
        if (k < 7) {
            wq.x = cvtpk(pA.x, pA.y);  wq.y = cvtpk(pA.z, pA.w);
            wq.z = cvtpk(pB.x, pB.y);  wq.w = cvtpk(pB.z, pB.w);
        }

        // (4) W fragments for ks=2k+2 (reuses bA regs, dead after step 2)
        if (k < 7) {
#pragma unroll
            for (int jj = 0; jj < 4; jj++)
                bA[jj] = Wp[((wave * 4 + jj) * 16 + (2 * k + 2)) * 64 + lane];
        }

        // (5) X(k+2) HBM prefetch — youngest in the vm FIFO
        if (k < 6) { pA = Xr[(k + 2) * 16]; pB = Xr[(k + 2) * 16 + 1]; }

        // (6) ks=2k+1: ds_read + MFMA on bB (wait is older than bA'/X -> no drain)
#pragma unroll
        for (int i = 0; i < 4; i++)
            af[i] = *reinterpret_cast<const bf16x8*>(
                &Ab[(i * 16 + l15) * ST + 32 + quad * 8]);
#pragma unroll
        for (int jj = 0; jj < 4; jj++) {
            bf16x8 bfr = __builtin_bit_cast(bf16x8, bB[jj]);
#pragma unroll
            for (int i = 0; i < 4; i++)
                acc[i][jj] = __builtin_amdgcn_mfma_f32_16x16x32_bf16(
                    af[i], bfr, acc[i][jj], 0, 0, 0);
        }

        // (7) stage X(k+1) into the buffer read next step
        if (k < 7)
            *reinterpret_cast<uint4*>((k & 1) ? Aw0 : Aw1) = wq;

        // (8) LDS-only barrier; HBM/L2 prefetches stay in flight
        if (k < 7) LDS_BARRIER();
    }

    // ---- epilogue: scores (this wave owns H-cols wave*64 .. wave*64+63) ----
    float hb[4], hv[4];
#pragma unroll
    for (int jj = 0; jj < 4; jj++) {
        int h = wave * 64 + jj * 16 + l15;
        hb[jj] = bias[b * HDIM + h];
        hv[jj] = v[h];
    }
    float s_acc[16];
#pragma unroll
    for (int x = 0; x < 16; x++) s_acc[x] = 0.f;
#pragma unroll
    for (int i = 0; i < 4; i++)
#pragma unroll
        for (int jj = 0; jj < 4; jj++)
#pragma unroll
            for (int rr = 0; rr < 4; rr++)
                s_acc[i * 4 + rr] += hv[jj] * tanh_fast(acc[i][jj][rr] + hb[jj]);

#pragma unroll
    for (int m = 1; m < 16; m <<= 1)
#pragma unroll
        for (int x = 0; x < 16; x++)
            s_acc[x] += __shfl_xor(s_acc[x], m, 16);

    if (l15 == 0) {
#pragma unroll
        for (int x = 0; x < 16; x++) {
            int i = x >> 2, rr = x & 3;
            sred[wave][i * 16 + quad * 4 + rr] = s_acc[x];
        }
    }
    __syncthreads();

    // ---- phase B: local softmax over 64 scores (first 64 threads) ----
    if (tid < 64) {
        float sc = sred[0][tid] + sred[1][tid] + sred[2][tid] + sred[3][tid]
                 + sred[4][tid] + sred[5][tid] + sred[6][tid] + sred[7][tid];
        float mx = sc;
#pragma unroll
        for (int m = 1; m < 64; m <<= 1) mx = fmaxf(mx, __shfl_xor(mx, m, 64));
        float p = __builtin_amdgcn_exp2f((sc - mx) * 1.44269504088896f);
        float l = p;
#pragma unroll
        for (int m = 1; m < 64; m <<= 1) l += __shfl_xor(l, m, 64);
        pbuf[tid] = p;
        if (tid == 0) { mpart[blk] = mx; lpart[blk] = l; }
    }
    __syncthreads();

    // ---- phase C: weighted sum of X tile (L2-hot re-read, fp32 precision) ----
    // thread tid owns output column e=tid; per row the 512 threads read 2 KB
    // contiguous -> fully coalesced.
    const float* Xc = X + row0 * EDIM + tid;
    float a0c = 0.f, a1c = 0.f;
#pragma unroll 2
    for (int s = 0; s < 64; s += 8) {
        float x[8];
#pragma unroll
        for (int kk = 0; kk < 8; kk++) x[kk] = Xc[(s + kk) * EDIM];
#pragma unroll
        for (int kk = 0; kk < 8; kk += 2) {
            a0c = fmaf(pbuf[s + kk],     x[kk],     a0c);
            a1c = fmaf(pbuf[s + kk + 1], x[kk + 1], a1c);
        }
    }
    cpart[(long)blk * EDIM + tid] = a0c + a1c;
}

// ---------------------------------------------------------------------------
// combine_k: per batch, merge 64 chunk partials (flash-decoding style).
// out[b][e] = sum_i exp(m_i - M) * c_i[e] / sum_i exp(m_i - M) * l_i
// ---------------------------------------------------------------------------
__global__ __launch_bounds__(256) void combine_k(const float* __restrict__ cpart,
                                                 const float* __restrict__ mpart,
                                                 const float* __restrict__ lpart,
                                                 float* __restrict__ out) {
    __shared__ float wbuf[64];
    __shared__ float linv_s;
    int b = blockIdx.x, t = threadIdx.x;
    if (t < 64) {
        float m = mpart[b * 64 + t];
        float M = m;
#pragma unroll
        for (int k = 1; k < 64; k <<= 1) M = fmaxf(M, __shfl_xor(M, k, 64));
        float w = __builtin_amdgcn_exp2f((m - M) * 1.44269504088896f);
        float lw = lpart[b * 64 + t] * w;
        float L = lw;
#pragma unroll
        for (int k = 1; k < 64; k <<= 1) L += __shfl_xor(L, k, 64);
        wbuf[t] = w;
        if (t == 0) linv_s = 1.0f / L;
    }
    __syncthreads();
    const float2* cp = reinterpret_cast<const float2*>(cpart) + (long)b * 64 * 256 + t;
    float ax = 0.f, ay = 0.f;
#pragma unroll 2
    for (int i = 0; i < 64; i += 8) {
        float2 x[8];
#pragma unroll
        for (int k = 0; k < 8; k++) x[k] = cp[(i + k) * 256];
#pragma unroll
        for (int k = 0; k < 8; k++) {
            float w = wbuf[i + k];
            ax = fmaf(w, x[k].x, ax);
            ay = fmaf(w, x[k].y, ay);
        }
    }
    float inv = linv_s;
    reinterpret_cast<float2*>(out)[b * 256 + t] = make_float2(ax * inv, ay * inv);
}

// ---------------------------------------------------------------------------
extern "C" void kernel_launch(void* const* d_in, const int* in_sizes, int n_in,
                              void* d_out, int out_size, void* d_ws, size_t ws_size,
                              hipStream_t stream) {
    const float* X      = (const float*)d_in[0];
    const float* dec    = (const float*)d_in[1];
    const float* W_enc  = (const float*)d_in[2];
    const float* b_enc  = (const float*)d_in[3];
    const float* W_dec  = (const float*)d_in[4];
    const float* b_dec  = (const float*)d_in[5];
    const float* v      = (const float*)d_in[6];
    float* out = (float*)d_out;

    char* ws = (char*)d_ws;
    uint4* wpack    = (uint4*)ws;                          // 512 KB
    float* dec_bias = (float*)(ws + (512 << 10));          // 64 KB
    float* cpart    = (float*)(ws + (576 << 10));          // 2048*512*4 = 4 MB
    float* mpart    = (float*)(ws + (576 << 10) + (4096 << 10));   // 8 KB
    float* lpart    = (float*)(ws + (576 << 10) + (4104 << 10));   // 8 KB

    prep_kernel  <<<4224, 256, 0, stream>>>(W_enc, wpack, dec, W_dec, b_enc, b_dec,
                                            dec_bias);
    fused_kernel <<<NBLK, 512, 0, stream>>>(X, wpack, dec_bias, v, cpart, mpart, lpart);
    combine_k    <<<BATCH, 256, 0, stream>>>(cpart, mpart, lpart, out);
}

// Round 6
// 443.151 us; speedup vs baseline: 1.0339x; 1.0339x over previous
//
#include <hip/hip_runtime.h>
#include <hip/hip_bf16.h>

// Problem constants: B=32, S=4096, E=512, D=512, H=512
#define BATCH 32
#define SEQ   4096
#define EDIM  512
#define HDIM  512
#define NCHUNK 64                 // S-chunks of 64 rows per batch
#define NBLK  (BATCH * NCHUNK)    // 2048 fused blocks

typedef unsigned short u16;
typedef unsigned int   u32;

typedef __bf16 bf16x8 __attribute__((ext_vector_type(8)));
typedef float  f32x4  __attribute__((ext_vector_type(4)));

// one-instruction fp32x2 -> packed bf16x2 (RNE; bit-identical to manual RNE)
__device__ __forceinline__ u32 cvtpk(float lo, float hi) {
    u32 r;
    asm("v_cvt_pk_bf16_f32 %0, %1, %2" : "=v"(r) : "v"(lo), "v"(hi));
    return r;
}
__device__ __forceinline__ float tanh_fast(float x) {
    float e = __builtin_amdgcn_exp2f(x * 2.88539008177793f);
    return 1.0f - 2.0f * __builtin_amdgcn_rcpf(e + 1.0f);
}

// raw barrier: LDS-drain only. NOT __syncthreads() — that emits an implicit
// s_waitcnt vmcnt(0) which would drain our in-flight HBM/L2 prefetches at
// every step (the m97 barrier-drain trap). sched_barrier(0) pins the ds ops
// on the correct side of the asm wait (rule #18).
#define LDS_BARRIER() do {                                   \
    __builtin_amdgcn_sched_barrier(0);                       \
    asm volatile("s_waitcnt lgkmcnt(0)" ::: "memory");       \
    __builtin_amdgcn_s_barrier();                            \
    __builtin_amdgcn_sched_barrier(0);                       \
} while (0)

// ---------------------------------------------------------------------------
// prep_kernel: (a) dec_bias = dec @ W_dec^T + b_dec + b_enc   [blocks 0..4095]
//              (b) pack W_enc fp32 -> bf16 b-fragment layout  [blocks 4096..4223]
// wpack chunk id = (nsub*16 + kc)*64 + lane;
// lane holds W[nsub*16+(l&15)][kc*32+(l>>4)*8+j], j=0..7
// ---------------------------------------------------------------------------
__global__ void prep_kernel(const float* __restrict__ W_enc, uint4* __restrict__ wpack,
                            const float* __restrict__ dec, const float* __restrict__ Wd,
                            const float* __restrict__ b_enc, const float* __restrict__ b_dec,
                            float* __restrict__ dec_bias) {
    int bid = blockIdx.x;
    int t = threadIdx.x;
    if (bid < 4096) {
        int wave = t >> 6, lane = t & 63;
        int p = bid * 4 + wave;
        int b = p >> 9, h = p & 511;
        const float4* wr = reinterpret_cast<const float4*>(Wd)  + h * 128;
        const float4* dr = reinterpret_cast<const float4*>(dec) + b * 128;
        float4 w0 = wr[lane * 2], w1 = wr[lane * 2 + 1];
        float4 d0 = dr[lane * 2], d1 = dr[lane * 2 + 1];
        float s = w0.x * d0.x + w0.y * d0.y + w0.z * d0.z + w0.w * d0.w
                + w1.x * d1.x + w1.y * d1.y + w1.z * d1.z + w1.w * d1.w;
#pragma unroll
        for (int m = 1; m < 64; m <<= 1) s += __shfl_xor(s, m, 64);
        if (lane == 0) dec_bias[p] = s + b_dec[h] + b_enc[h];
    } else {
        int id   = (bid - 4096) * 256 + t;          // 32768 chunks
        int nsub = id >> 10;
        int rem  = id & 1023;
        int kc   = rem >> 6;
        int lane = rem & 63;
        int row  = nsub * 16 + (lane & 15);
        int col  = kc * 32 + (lane >> 4) * 8;
        const float* src = W_enc + row * EDIM + col;
        uint4 o;
        o.x = cvtpk(src[0], src[1]);
        o.y = cvtpk(src[2], src[3]);
        o.z = cvtpk(src[4], src[5]);
        o.w = cvtpk(src[6], src[7]);
        wpack[id] = o;
    }
}

// ---------------------------------------------------------------------------
// fused_kernel v6: 1024 threads / 16 waves per block; per block = (batch b,
// 64-row S-chunk); each wave owns a 64-row x 32-H-col output tile.
//  ROUND-5 POST-MORTEM: at 512 thr the acc tile is 64 regs/thread, leaving
//  only 64 arch VGPRs under the 128 cap — every pipelining attempt spilled
//  (v3, v5: WRITE_SIZE 107/112 MB). v6 halves acc to 32 (1024 threads) ->
//  arch budget 96: the full pipeline now fits (~100 total, ~25 slack).
//  Chunked software pipeline, per super-step k (2 K-steps, 8 total):
//    1. issue W(2k+2),W(2k+3) into Wn[4]     (L2; parity-swapped, no copies)
//    2. issue X(k+2) float4 -> pXn           (HBM; youngest in vm FIFO)
//    3. ds_read af lo + 8 MFMA on Wc[0..1]   (waits W(2k) only)
//    4. cvt pXc (=X(k+1)) via cvt_pk; ds_write_b64 -> buf[(k+1)&1]
//    5. ds_read af hi + 8 MFMA on Wc[2..3]
//    6. LDS_BARRIER (lgkmcnt only; W/X prefetches stay in flight)
//  FIFO invariant: W issued before X each step -> no W-wait ever drains the
//  X HBM prefetch; cvt's X-wait drains only already-consumed older W.
//  LDS: 2 x 64 x ST(72) u16 = 18 KB chunks (+sred 4 KB, cbuf 2 KB, pbuf).
//  Bank maps at ST=72 (dword stride 36 == 4 mod 32): af ds_read_b128 spreads
//  8 dwords/bank (optimal); staging ds_write_b64 4 dwords/bank (balanced).
//  Regs: acc 32 + Wc/Wn 32 + pX 8 + af 16 transient + addr ~12 ~= 100 < 128.
//  Occupancy: 1 block/CU (2048-thread cap), 16 waves/CU = 4 waves/SIMD.
//  mfma_f32_16x16x32_bf16: A[m=l&15][k=(l>>4)*8+j]; C/D: m=(l>>4)*4+r, n=l&15.
// ---------------------------------------------------------------------------
#define ST 72

#define KSTEP(k, Wc, Wn, pXc, pXn)                                              \
    {                                                                           \
        const u16* Ab_ = &Abuf[(k) & 1][0];                                     \
        if ((k) < 7) {                                                          \
            Wn[0] = Wq[(2 * (k) + 2) * 64];                                     \
            Wn[1] = Wq[(16 + 2 * (k) + 2) * 64];                                \
            Wn[2] = Wq[(2 * (k) + 3) * 64];                                     \
            Wn[3] = Wq[(16 + 2 * (k) + 3) * 64];                                \
        }                                                                       \
        if ((k) < 6) pXn = Xr[((k) + 2) * 16];                                  \
        bf16x8 af_[4];                                                          \
        _Pragma("unroll")                                                       \
        for (int i = 0; i < 4; i++)                                             \
            af_[i] = *reinterpret_cast<const bf16x8*>(                          \
                &Ab_[(i * 16 + l15) * ST + quad * 8]);                          \
        _Pragma("unroll")                                                       \
        for (int jj = 0; jj < 2; jj++) {                                        \
            bf16x8 bfr = __builtin_bit_cast(bf16x8, Wc[jj]);                    \
            _Pragma("unroll")                                                   \
            for (int i = 0; i < 4; i++)                                         \
                acc[i][jj] = __builtin_amdgcn_mfma_f32_16x16x32_bf16(           \
                    af_[i], bfr, acc[i][jj], 0, 0, 0);                          \
        }                                                                       \
        if ((k) < 7) {                                                          \
            uint2 wq_;                                                          \
            wq_.x = cvtpk(pXc.x, pXc.y);                                        \
            wq_.y = cvtpk(pXc.z, pXc.w);                                        \
            *reinterpret_cast<uint2*>(                                          \
                &Abuf[((k) + 1) & 1][r * ST + c4 * 4]) = wq_;                   \
        }                                                                       \
        _Pragma("unroll")                                                       \
        for (int i = 0; i < 4; i++)                                             \
            af_[i] = *reinterpret_cast<const bf16x8*>(                          \
                &Ab_[(i * 16 + l15) * ST + 32 + quad * 8]);                     \
        _Pragma("unroll")                                                       \
        for (int jj = 0; jj < 2; jj++) {                                        \
            bf16x8 bfr = __builtin_bit_cast(bf16x8, Wc[2 + jj]);                \
            _Pragma("unroll")                                                   \
            for (int i = 0; i < 4; i++)                                         \
                acc[i][jj] = __builtin_amdgcn_mfma_f32_16x16x32_bf16(           \
                    af_[i], bfr, acc[i][jj], 0, 0, 0);                          \
        }                                                                       \
        if ((k) < 7) LDS_BARRIER();                                             \
    }

__global__ __launch_bounds__(1024, 4) void fused_kernel(
    const float* __restrict__ X, const uint4* __restrict__ Wp,
    const float* __restrict__ bias, const float* __restrict__ v,
    float* __restrict__ cpart, float* __restrict__ mpart, float* __restrict__ lpart)
{
    __shared__ alignas(16) u16 Abuf[2][64 * ST];     // 2 x 9216 B
    __shared__ float sred[16][64];                   // 4 KB
    __shared__ float pbuf[64];
    __shared__ float cbuf[EDIM];                     // 2 KB (phase-C halves)

    const int tid  = threadIdx.x;
    const int wave = tid >> 6, lane = tid & 63;
    const int quad = lane >> 4, l15 = lane & 15;
    const int blk  = blockIdx.x;          // 2048
    const int b    = blk >> 6;
    const long row0 = (long)blk * 64;
    const float4* X4 = reinterpret_cast<const float4*>(X + row0 * EDIM);

    // staging map: thread -> row r (0..63), 4-float group c4 (0..15) within
    // the 64-col super-chunk. Each thread stages ONE float4 per chunk.
    const int r  = tid >> 4;
    const int c4 = tid & 15;
    const float4* Xr = X4 + r * 128 + c4;            // + k*16 per chunk
    // per-thread W pointer: wave's H-slice = nsub wave*2 + jj (jj=0,1);
    // index offset (jj*16 + ks)*64 uint4s, compile-time per unrolled step.
    const uint4* Wq = Wp + (wave * 2) * 16 * 64 + lane;

    // ---- prologue: X(0) raw; W(0..1); X(1); cvt+stage X(0) -> buf0 ----
    float4 x0 = Xr[0];                               // oldest in vm FIFO
    uint4 W0a[4], W1a[4];
    W0a[0] = Wq[0];
    W0a[1] = Wq[16 * 64];
    W0a[2] = Wq[64];
    W0a[3] = Wq[17 * 64];
    float4 pX0 = Xr[16], pX1;                        // X chunk 1 (youngest)
    {
        uint2 w;
        w.x = cvtpk(x0.x, x0.y);
        w.y = cvtpk(x0.z, x0.w);
        *reinterpret_cast<uint2*>(&Abuf[0][r * ST + c4 * 4]) = w;
    }
    f32x4 acc[4][2] = {};                 // [msub][nsub]: m=64, n=32 per wave
    LDS_BARRIER();

    // ---- main loop: 8 super-steps, parity-swapped register sets ----
    KSTEP(0, W0a, W1a, pX0, pX1)
    KSTEP(1, W1a, W0a, pX1, pX0)
    KSTEP(2, W0a, W1a, pX0, pX1)
    KSTEP(3, W1a, W0a, pX1, pX0)
    KSTEP(4, W0a, W1a, pX0, pX1)
    KSTEP(5, W1a, W0a, pX1, pX0)
    KSTEP(6, W0a, W1a, pX0, pX1)
    KSTEP(7, W1a, W0a, pX1, pX0)

    // ---- epilogue: scores (wave owns H-cols wave*32 .. wave*32+31) ----
    float hb[2], hv[2];
#pragma unroll
    for (int jj = 0; jj < 2; jj++) {
        int h = wave * 32 + jj * 16 + l15;
        hb[jj] = bias[b * HDIM + h];
        hv[jj] = v[h];
    }
    float s_acc[16];
#pragma unroll
    for (int x = 0; x < 16; x++) s_acc[x] = 0.f;
#pragma unroll
    for (int i = 0; i < 4; i++)
#pragma unroll
        for (int jj = 0; jj < 2; jj++)
#pragma unroll
            for (int rr = 0; rr < 4; rr++)
                s_acc[i * 4 + rr] += hv[jj] * tanh_fast(acc[i][jj][rr] + hb[jj]);

#pragma unroll
    for (int m = 1; m < 16; m <<= 1)
#pragma unroll
        for (int x = 0; x < 16; x++)
            s_acc[x] += __shfl_xor(s_acc[x], m, 16);

    if (l15 == 0) {
#pragma unroll
        for (int x = 0; x < 16; x++) {
            int i = x >> 2, rr = x & 3;
            sred[wave][i * 16 + quad * 4 + rr] = s_acc[x];
        }
    }
    __syncthreads();

    // ---- phase B: local softmax over 64 scores (first 64 threads) ----
    if (tid < 64) {
        float sc = 0.f;
#pragma unroll
        for (int w = 0; w < 16; w++) sc += sred[w][tid];
        float mx = sc;
#pragma unroll
        for (int m = 1; m < 64; m <<= 1) mx = fmaxf(mx, __shfl_xor(mx, m, 64));
        float p = __builtin_amdgcn_exp2f((sc - mx) * 1.44269504088896f);
        float l = p;
#pragma unroll
        for (int m = 1; m < 64; m <<= 1) l += __shfl_xor(l, m, 64);
        pbuf[tid] = p;
        if (tid == 0) { mpart[blk] = mx; lpart[blk] = l; }
    }
    __syncthreads();

    // ---- phase C: weighted sum of X tile (L2-hot re-read, fp32 precision).
    // 1024 threads: e = tid&511 owns a column; half = tid>>9 handles 32 rows;
    // halves combined through cbuf. Per row 512 lanes read 2 KB contiguous.
    {
        const int e    = tid & 511;
        const int half = tid >> 9;
        const float* Xc = X + row0 * EDIM + (long)(half * 32) * EDIM + e;
        float a0 = 0.f, a1 = 0.f;
#pragma unroll 2
        for (int s = 0; s < 32; s += 8) {
            float x[8];
#pragma unroll
            for (int kk = 0; kk < 8; kk++) x[kk] = Xc[(s + kk) * EDIM];
#pragma unroll
            for (int kk = 0; kk < 8; kk += 2) {
                a0 = fmaf(pbuf[half * 32 + s + kk],     x[kk],     a0);
                a1 = fmaf(pbuf[half * 32 + s + kk + 1], x[kk + 1], a1);
            }
        }
        float tot = a0 + a1;
        if (half) cbuf[e] = tot;
        __syncthreads();
        if (!half) cpart[(long)blk * EDIM + e] = tot + cbuf[e];
    }
}

// ---------------------------------------------------------------------------
// combine_k: per batch, merge 64 chunk partials (flash-decoding style).
// out[b][e] = sum_i exp(m_i - M) * c_i[e] / sum_i exp(m_i - M) * l_i
// ---------------------------------------------------------------------------
__global__ __launch_bounds__(256) void combine_k(const float* __restrict__ cpart,
                                                 const float* __restrict__ mpart,
                                                 const float* __restrict__ lpart,
                                                 float* __restrict__ out) {
    __shared__ float wbuf[64];
    __shared__ float linv_s;
    int b = blockIdx.x, t = threadIdx.x;
    if (t < 64) {
        float m = mpart[b * 64 + t];
        float M = m;
#pragma unroll
        for (int k = 1; k < 64; k <<= 1) M = fmaxf(M, __shfl_xor(M, k, 64));
        float w = __builtin_amdgcn_exp2f((m - M) * 1.44269504088896f);
        float lw = lpart[b * 64 + t] * w;
        float L = lw;
#pragma unroll
        for (int k = 1; k < 64; k <<= 1) L += __shfl_xor(L, k, 64);
        wbuf[t] = w;
        if (t == 0) linv_s = 1.0f / L;
    }
    __syncthreads();
    const float2* cp = reinterpret_cast<const float2*>(cpart) + (long)b * 64 * 256 + t;
    float ax = 0.f, ay = 0.f;
#pragma unroll 2
    for (int i = 0; i < 64; i += 8) {
        float2 x[8];
#pragma unroll
        for (int k = 0; k < 8; k++) x[k] = cp[(i + k) * 256];
#pragma unroll
        for (int k = 0; k < 8; k++) {
            float w = wbuf[i + k];
            ax = fmaf(w, x[k].x, ax);
            ay = fmaf(w, x[k].y, ay);
        }
    }
    float inv = linv_s;
    reinterpret_cast<float2*>(out)[b * 256 + t] = make_float2(ax * inv, ay * inv);
}

// ---------------------------------------------------------------------------
extern "C" void kernel_launch(void* const* d_in, const int* in_sizes, int n_in,
                              void* d_out, int out_size, void* d_ws, size_t ws_size,
                              hipStream_t stream) {
    const float* X      = (const float*)d_in[0];
    const float* dec    = (const float*)d_in[1];
    const float* W_enc  = (const float*)d_in[2];
    const float* b_enc  = (const float*)d_in[3];
    const float* W_dec  = (const float*)d_in[4];
    const float* b_dec  = (const float*)d_in[5];
    const float* v      = (const float*)d_in[6];
    float* out = (float*)d_out;

    char* ws = (char*)d_ws;
    uint4* wpack    = (uint4*)ws;                          // 512 KB
    float* dec_bias = (float*)(ws + (512 << 10));          // 64 KB
    float* cpart    = (float*)(ws + (576 << 10));          // 2048*512*4 = 4 MB
    float* mpart    = (float*)(ws + (576 << 10) + (4096 << 10));   // 8 KB
    float* lpart    = (float*)(ws + (576 << 10) + (4104 << 10));   // 8 KB

    prep_kernel  <<<4224, 256, 0, stream>>>(W_enc, wpack, dec, W_dec, b_enc, b_dec,
                                            dec_bias);
    fused_kernel <<<NBLK, 1024, 0, stream>>>(X, wpack, dec_bias, v, cpart, mpart, lpart);
    combine_k    <<<BATCH, 256, 0, stream>>>(cpart, mpart, lpart, out);
}